// Round 8
// baseline (6125973.438 us; speedup 1.0000x reference)
//
#include <hip/hip_runtime.h>
#include <stdint.h>
#include <stddef.h>

// ---------------------------------------------------------------------------
// LSTM (B=64, T=1024, I=256, H=512) + attention pooling on MI355X (gfx950).
// k_lstm v7: 8 chains x 8 blocks (512 thr). Chain c = batches c*8..+7,
// blocks {c, c+8, ..., c+56}; under round-robin dispatch all land on XCD c.
// Co-residency is verified via HW_REG_XCC_ID (hardware register, replay-
// stale-proof) published once through the proven sc0 sc1 LLC path. Verdict
// is computed identically by every block from write-once data:
//   local  : h + flags with sc0 only  -> XCD-L2 coherent, ~200cyc RTs
//   fallbk : h + flags with sc0 sc1   -> LLC path (R5/R6 behavior, correct)
// Within-dispatch is the only coherence scope that matters: the HIP runtime
// flushes/invalidates L2s at dispatch boundaries (this is what made all
// prior inter-kernel hs handoffs work), so no stale lines across replays,
// and k_attn sees hs after k_lstm's end-of-dispatch flush.
// ---------------------------------------------------------------------------

typedef _Float16 f16_t;
typedef _Float16 half8 __attribute__((ext_vector_type(8)));
typedef float f32x4 __attribute__((ext_vector_type(4)));

#define MFMA16(a, b, c) __builtin_amdgcn_mfma_f32_16x16x32_f16((a), (b), (c), 0, 0, 0)

static constexpr int BATCH = 64;
static constexpr int TLEN = 1024;
static constexpr int IDIM = 256;
static constexpr int HDIM = 512;

__device__ __forceinline__ float sigf(float x) { return 1.f / (1.f + __expf(-x)); }
__device__ __forceinline__ float tanh_fast(float x) {
  float e = __expf(2.f * fabsf(x));
  float t = 1.f - 2.f / (e + 1.f);
  return copysignf(t, x);
}
__device__ __forceinline__ half8 load_cvt8(const float* p) {
  f32x4 a = *(const f32x4*)p;
  f32x4 b = *(const f32x4*)(p + 4);
  half8 r;
#pragma unroll
  for (int j = 0; j < 4; ++j) { r[j] = (f16_t)a[j]; r[4 + j] = (f16_t)b[j]; }
  return r;
}

// ---------------------------------------------------------------------------
__global__ __launch_bounds__(256) void k_prep_x(const float* __restrict__ x,
                                                f16_t* __restrict__ xT) {
  __shared__ f16_t sx[64][IDIM + 8];
  const int t = blockIdx.x;
  const int tid = threadIdx.x;
#pragma unroll 4
  for (int b = 0; b < 64; ++b)
    sx[b][tid] = (f16_t)x[((size_t)b * TLEN + t) * IDIM + tid];
  __syncthreads();
#pragma unroll
  for (int it = 0; it < 8; ++it) {
    const int c = it * 256 + tid;      // c = kk4*64 + b
    const int b = c & 63, kk4 = c >> 6;
    half8 v = *(const half8*)&sx[b][kk4 * 8];
    *(half8*)(xT + (((size_t)t * 32 + kk4) * 64 + b) * 8) = v;
  }
}

__global__ __launch_bounds__(256) void k_prep_w(const float* __restrict__ Wa,
                                                f16_t* __restrict__ WaT) {
  const int id = blockIdx.x * 256 + threadIdx.x;   // 0..32767
  const int n = id & 511, kk4 = id >> 9;
  half8 v = load_cvt8(&Wa[(size_t)n * HDIM + kk4 * 8]);
  *(half8*)(WaT + ((size_t)kk4 * HDIM + n) * 8) = v;
}

// WxA: W_ih pre-packed into per-(role,wave,tile,kk,lane) fp16 A-fragments.
__global__ __launch_bounds__(256) void k_prep_wx(const float* __restrict__ Wih,
                                                 f16_t* __restrict__ WxA) {
  const int id = blockIdx.x * 256 + threadIdx.x;   // 0..65535
  const int L = id & 63, kk = (id >> 6) & 7, tl = (id >> 9) & 1;
  const int w = (id >> 10) & 7, R = (id >> 13) & 7;
  const int col = L & 15, q = L >> 4;
  const int row = (col & 3) * HDIM + R * 64 + w * 8 + tl * 4 + (col >> 2);
  half8 v = load_cvt8(&Wih[(size_t)row * IDIM + kk * 32 + q * 8]);
  *(half8*)(WxA + (size_t)id * 8) = v;
}

// ---------------------------------------------------------------------------
__global__ __launch_bounds__(512) void k_lstm(
    const float* __restrict__ Whh, const f16_t* __restrict__ WxA,
    const float* __restrict__ bih, const float* __restrict__ bhh,
    const f16_t* __restrict__ xT, f16_t* __restrict__ hs,
    unsigned int* __restrict__ bar) {
  const int tid = threadIdx.x;
  const int w = tid >> 6;
  const int L = tid & 63;
  const int q = L >> 4, col = L & 15;
  const int c = blockIdx.x & 7;              // chain (XCD under %8 mapping)
  const int R = blockIdx.x >> 3;             // role: units R*64..+63
  const int lb = tid & 7, uc = tid >> 3;     // coop-load role

  unsigned int* flags = bar + c * 16;        // 64B line per chain
  unsigned int* xpub  = bar + 128 + c * 16;  // xcc publish line per chain

  __shared__ __align__(16) f16_t hin[4096];      // [uc 0..63][lb 0..7][8] 8KB
  __shared__ __align__(16) f16_t hout[8][64];    // [batch][unit_local] 1KB
  __shared__ int modeSh;

  // ---- startup: publish XCC_ID via LLC, all blocks compute same verdict ---
  if (tid == 0) {
    unsigned my_xcc;
    asm volatile("s_getreg_b32 %0, hwreg(HW_REG_XCC_ID)" : "=s"(my_xcc));
    my_xcc &= 0xFu;
    unsigned tagged = 0xA5A50000u | my_xcc;
    asm volatile("global_store_dword %0, %1, off sc0 sc1\n\ts_waitcnt vmcnt(0)"
                 :: "v"(xpub + R), "v"(tagged) : "memory");
    unsigned seen[8];
    bool all = false;
    for (int it = 0; it < (1 << 20) && !all; ++it) {
      all = true;
      for (int j = 0; j < 8; ++j) {
        unsigned v;
        asm volatile("global_load_dword %0, %1, off sc0 sc1\n\ts_waitcnt vmcnt(0)"
                     : "=&v"(v) : "v"(xpub + j) : "memory");
        seen[j] = v;
        all &= ((v & 0xFFFF0000u) == 0xA5A50000u);
      }
      if (!all) __builtin_amdgcn_s_sleep(16);
    }
    bool same = all;
    if (all)
      for (int j = 1; j < 8; ++j) same &= ((seen[j] & 0xFu) == (seen[0] & 0xFu));
    modeSh = same ? 1 : 2;
  }
  __syncthreads();
  const bool local = (modeSh == 1);

  // ---------------- persistent weights / biases ---------------------------
  half8 wAh[32];                              // [tile][kk] W_hh A-fragments
#pragma unroll
  for (int tl = 0; tl < 2; ++tl) {
    const int arow = (col & 3) * HDIM + R * 64 + w * 8 + tl * 4 + (col >> 2);
#pragma unroll
    for (int kk = 0; kk < 16; ++kk)
      wAh[tl * 16 + kk] = load_cvt8(&Whh[(size_t)arow * HDIM + kk * 32 + q * 8]);
  }
  float pb[2][4];
#pragma unroll
  for (int tl = 0; tl < 2; ++tl) {
    const int u = R * 64 + w * 8 + tl * 4 + q;
#pragma unroll
    for (int r = 0; r < 4; ++r) pb[tl][r] = bih[r * HDIM + u] + bhh[r * HDIM + u];
  }

  auto xgemm = [&](int tt, f32x4* xa) {
    f32x4 r0 = {0.f, 0.f, 0.f, 0.f}, r1 = {0.f, 0.f, 0.f, 0.f};
    const size_t wbase = ((size_t)(R * 8 + w) * 2) * 8 * 64 * 8;
#pragma unroll
    for (int kk = 0; kk < 8; ++kk) {
      half8 bf = *(const half8*)(xT +
          (((size_t)(tt - 1) * 32 + kk * 4 + q) * 64 + c * 8 + (col & 7)) * 8);
      half8 a0 = *(const half8*)(WxA + wbase + ((size_t)kk * 64 + L) * 8);
      half8 a1 = *(const half8*)(WxA + wbase + ((size_t)(8 + kk) * 64 + L) * 8);
      r0 = MFMA16(a0, bf, r0);
      r1 = MFMA16(a1, bf, r1);
    }
    xa[0] = r0; xa[1] = r1;
  };

  float cst[2] = {0.f, 0.f};
  f32x4 xacc[2];
  xgemm(1, xacc);

  for (int t = 1; t <= TLEN; ++t) {
    if (t > 1) {
      // ---- poll all 8 producer flags >= t-1 (8 lanes, dup over 64) ----
      const unsigned tgt = (unsigned)(t - 1);
      const unsigned int* fp = flags + (L & 7);
      int g = 0;
      for (;;) {
        unsigned v;
        if (local)
          asm volatile("global_load_dword %0, %1, off sc0\n\ts_waitcnt vmcnt(0)"
                       : "=&v"(v) : "v"(fp) : "memory");
        else
          asm volatile("global_load_dword %0, %1, off sc0 sc1\n\ts_waitcnt vmcnt(0)"
                       : "=&v"(v) : "v"(fp) : "memory");
        if (__ballot(v >= tgt) == ~0ull) break;
        if (++g > (1 << 16)) break;            // bounded: fail fast, not hang
      }
      // ---- coop-load h(t-1): 8KB block-wide, 16B/thread -> LDS ----
      const f16_t* src = hs + ((size_t)(t - 1) * BATCH + c * 8 + lb) * HDIM
                         + uc * 8;
      f32x4 hv;
      if (local)
        asm volatile("global_load_dwordx4 %0, %1, off sc0\n\ts_waitcnt vmcnt(0)"
                     : "=&v"(hv) : "v"(src) : "memory");
      else
        asm volatile("global_load_dwordx4 %0, %1, off sc0 sc1\n\ts_waitcnt vmcnt(0)"
                     : "=&v"(hv) : "v"(src) : "memory");
      *(f32x4*)&hin[tid * 8] = hv;
    }
    __syncthreads();                           // hin ready

    f32x4 acc0, acc1;
    if (t > 1) {
      f32x4 A0 = xacc[0], B0 = {0.f, 0.f, 0.f, 0.f};
      f32x4 A1 = xacc[1], B1 = {0.f, 0.f, 0.f, 0.f};
#pragma unroll
      for (int kk = 0; kk < 16; kk += 2) {
        half8 ba = *(const half8*)&hin[((kk * 4 + q) * 8 + (col & 7)) * 8];
        half8 bb = *(const half8*)&hin[(((kk + 1) * 4 + q) * 8 + (col & 7)) * 8];
        A0 = MFMA16(wAh[kk], ba, A0);
        A1 = MFMA16(wAh[16 + kk], ba, A1);
        B0 = MFMA16(wAh[kk + 1], bb, B0);
        B1 = MFMA16(wAh[16 + kk + 1], bb, B1);
      }
      acc0 = A0 + B0;
      acc1 = A1 + B1;
    } else {
      acc0 = xacc[0];
      acc1 = xacc[1];
    }

#pragma unroll
    for (int tl = 0; tl < 2; ++tl) {
      const f32x4 a = tl ? acc1 : acc0;
      const float ig = sigf(a[0] + pb[tl][0]);
      const float fg = sigf(a[1] + pb[tl][1]);
      const float gg = tanh_fast(a[2] + pb[tl][2]);
      const float og = sigf(a[3] + pb[tl][3]);
      cst[tl] = fg * cst[tl] + ig * gg;
      const float hval = og * tanh_fast(cst[tl]);
      if (col < 8) hout[col][w * 8 + tl * 4 + q] = (f16_t)hval;
    }
    __syncthreads();                           // hout ready, hin consumed

    // ---- wave 0: 1KB store (16 x 64B lines), drain, flag = t ----
    if (w == 0) {
      const int sb = L >> 3, ch = L & 7;
      f32x4 v = *(const f32x4*)&hout[sb][ch * 8];
      f16_t* dst = hs + ((size_t)t * BATCH + c * 8 + sb) * HDIM + R * 64 + ch * 8;
      if (local)
        asm volatile("global_store_dwordx4 %0, %1, off sc0"
                     :: "v"(dst), "v"(v) : "memory");
      else
        asm volatile("global_store_dwordx4 %0, %1, off sc0 sc1"
                     :: "v"(dst), "v"(v) : "memory");
      asm volatile("s_waitcnt vmcnt(0)" ::: "memory");
      if (tid == 0) {
        unsigned tv = (unsigned)t;
        if (local)
          asm volatile("global_store_dword %0, %1, off sc0"
                       :: "v"(flags + R), "v"(tv) : "memory");
        else
          asm volatile("global_store_dword %0, %1, off sc0 sc1"
                       :: "v"(flags + R), "v"(tv) : "memory");
      }
    }
    // x-projection for the NEXT step (cached loads, off critical path)
    if (t < TLEN) xgemm(t + 1, xacc);
  }
}

// ---------------------------------------------------------------------------
__global__ __launch_bounds__(256) void k_attn(
    const f16_t* __restrict__ hse, const f16_t* __restrict__ WaT,
    const float* __restrict__ battn, f16_t* __restrict__ E) {
  const int w = threadIdx.x >> 6;
  const int L = threadIdx.x & 63;
  const int q = L >> 4, col = L & 15;
  const int m0 = blockIdx.x * 64 + w * 16;   // r rows (r = t*64+b)
  const int n0 = blockIdx.y * 64;            // h cols

  f32x4 acc[4];
#pragma unroll
  for (int nt = 0; nt < 4; ++nt) acc[nt] = {0.f, 0.f, 0.f, 0.f};

#pragma unroll 4
  for (int kk = 0; kk < 16; ++kk) {          // K = 512
    half8 af = *(const half8*)(hse + (size_t)(m0 + col) * HDIM + kk * 32 + q * 8);
#pragma unroll
    for (int nt = 0; nt < 4; ++nt) {
      half8 bf = *(const half8*)(WaT +
          ((size_t)(kk * 4 + q) * HDIM + n0 + nt * 16 + col) * 8);
      acc[nt] = MFMA16(af, bf, acc[nt]);
    }
  }
#pragma unroll
  for (int nt = 0; nt < 4; ++nt) {
    const int h = n0 + nt * 16 + col;
    const float bias = battn[h];
#pragma unroll
    for (int r = 0; r < 4; ++r) {
      const int m = m0 + q * 4 + r;
      E[(size_t)m * HDIM + h] = (f16_t)__expf(tanh_fast(acc[nt][r] + bias));
    }
  }
}

__global__ __launch_bounds__(256) void k_pool(
    const f16_t* __restrict__ E, const f16_t* __restrict__ hse,
    float* __restrict__ pnum, float* __restrict__ pden) {
  const int b = blockIdx.x;
  const int hc = blockIdx.y;
  const int tc = blockIdx.z;
  const int h = hc * 256 + threadIdx.x;
  float num = 0.f, den = 0.f;
#pragma unroll 4
  for (int tt = 0; tt < 256; ++tt) {
    const int t = tc * 256 + tt;
    const size_t idx = ((size_t)t * BATCH + b) * HDIM + h;
    const float e = (float)E[idx];
    const float hv = (float)hse[idx];
    den += e;
    num += e * hv;
  }
  const size_t pi = ((size_t)tc * BATCH + b) * HDIM + h;
  pnum[pi] = num;
  pden[pi] = den;
}

__global__ __launch_bounds__(256) void k_final(
    const float* __restrict__ pnum, const float* __restrict__ pden,
    float* __restrict__ out) {
  const int i = blockIdx.x * 256 + threadIdx.x;   // b*512+h
  float n = 0.f, d = 0.f;
#pragma unroll
  for (int z = 0; z < 4; ++z) {
    n += pnum[(size_t)z * 32768 + i];
    d += pden[(size_t)z * 32768 + i];
  }
  out[i] = n / d;
}

// ---------------------------------------------------------------------------
extern "C" void kernel_launch(void* const* d_in, const int* in_sizes, int n_in,
                              void* d_out, int out_size, void* d_ws, size_t ws_size,
                              hipStream_t stream) {
  const float* x   = (const float*)d_in[0];
  const float* Wih = (const float*)d_in[1];
  const float* Whh = (const float*)d_in[2];
  const float* bih = (const float*)d_in[3];
  const float* bhh = (const float*)d_in[4];
  const float* Wat = (const float*)d_in[5];
  const float* bat = (const float*)d_in[6];
  float* out = (float*)d_out;

  char* ws = (char*)d_ws;
  const size_t REGA_BYTES = (size_t)64 * 1024 * 1024;   // xT(32M)+WxA(@48M); E later
  const size_t HS_BYTES = (size_t)(TLEN + 1) * BATCH * HDIM * sizeof(f16_t); // 67.2MB
  const size_t WAT_BYTES = (size_t)64 * HDIM * 8 * sizeof(f16_t);            // 512KB
  const size_t P_BYTES = (size_t)4 * BATCH * HDIM * sizeof(float);           // 512KB

  f16_t* xT  = (f16_t*)ws;
  f16_t* WxA = (f16_t*)(ws + 48 * 1024 * 1024);
  f16_t* E   = (f16_t*)ws;                          // post-lstm reuse
  f16_t* hs  = (f16_t*)(ws + REGA_BYTES);
  f16_t* WaT = (f16_t*)(ws + REGA_BYTES + HS_BYTES);
  float* pnum = (float*)(ws + REGA_BYTES + HS_BYTES + WAT_BYTES);
  float* pden = (float*)(ws + REGA_BYTES + HS_BYTES + WAT_BYTES + P_BYTES);
  unsigned int* bar = (unsigned int*)(ws + REGA_BYTES + HS_BYTES + WAT_BYTES + 2 * P_BYTES);

  hipMemsetAsync(bar, 0, 4096, stream);   // flags + xcc-publish lines

  k_prep_x<<<dim3(TLEN), 256, 0, stream>>>(x, xT);
  k_prep_w<<<dim3(128), 256, 0, stream>>>(Wat, WaT);
  k_prep_wx<<<dim3(256), 256, 0, stream>>>(Wih, WxA);
  k_lstm<<<dim3(64), 512, 0, stream>>>(Whh, WxA, bih, bhh, xT, hs, bar);

  const f16_t* hse = hs + (size_t)BATCH * HDIM;   // slab 1 == reference hs[0]
  k_attn<<<dim3(1024, 8), 256, 0, stream>>>(hse, WaT, bat, E);
  k_pool<<<dim3(64, 2, 4), 256, 0, stream>>>(E, hse, pnum, pden);
  k_final<<<dim3(128), 256, 0, stream>>>(pnum, pden, out);
}